// Round 2
// baseline (3091.725 us; speedup 1.0000x reference)
//
#include <hip/hip_runtime.h>
#include <hip/hip_bf16.h>

#define BB 65536
#define NFIELD 20
#define DATA_NEMB 10
#define SQL_NEMB 10
#define HID 64
#define KEXP 16
#define EPS 1e-5f
#define NBLK_GATE 256
#define GATE_IN (NFIELD * SQL_NEMB)
#define EXP_IN (NFIELD * DATA_NEMB)

// ---- ws layout (element offsets, 4B elements) ----
#define OFF_GCNT 0              // 16 int
#define OFF_SC1 64              // 16*64 f32
#define OFF_SH1 (OFF_SC1 + 1024)
#define OFF_SC2 (OFF_SH1 + 1024)
#define OFF_SH2 (OFF_SC2 + 1024)
#define OFF_SCP (OFF_SH2 + 1024) // 64
#define OFF_SHP (OFF_SCP + 64)   // 64
#define OFF_W2T (OFF_SHP + 64)   // 16*64*64 transposed e_w2
#define OFF_PW1T (OFF_W2T + 65536) // 64*64 transposed p_w1
#define OFF_IMP (OFF_PW1T + 4096)  // 256*16 importance partials
#define OFF_LIDX (OFF_IMP + 4096)  // 16*B int
#define OFF_LW (OFF_LIDX + (16 * BB)) // 16*B f32
#define OFF_HS (OFF_LW + (16 * BB))   // B*2*64 f32

// ---------------- prep: BN fold, transposes, counter zero ----------------
__global__ __launch_bounds__(256) void k_prep(
    const float* __restrict__ ew2, const float* __restrict__ pw1,
    const float* __restrict__ eb1, const float* __restrict__ eg1,
    const float* __restrict__ ebe1, const float* __restrict__ em1,
    const float* __restrict__ ev1,
    const float* __restrict__ eb2, const float* __restrict__ eg2,
    const float* __restrict__ ebe2, const float* __restrict__ em2,
    const float* __restrict__ ev2,
    const float* __restrict__ pb1, const float* __restrict__ pg,
    const float* __restrict__ pbe, const float* __restrict__ pm,
    const float* __restrict__ pv,
    float* __restrict__ wsf, int* __restrict__ gcnt)
{
    int gid = blockIdx.x * 256 + threadIdx.x;
    if (gid < 65536) {
        // W2t[k][h][i] = ew2[k][i][h]
        int k = gid >> 12, r = gid & 4095, h = r >> 6, i = r & 63;
        wsf[OFF_W2T + gid] = ew2[(k * HID + i) * HID + h];
    } else if (gid < 65536 + 4096) {
        int t = gid - 65536;
        int h = t >> 6, i = t & 63;
        wsf[OFF_PW1T + t] = pw1[i * HID + h];
    } else if (gid < 65536 + 4096 + 1024) {
        int t = gid - (65536 + 4096); // k*64+h
        float rs1 = rsqrtf(ev1[t] + EPS) * eg1[t];
        wsf[OFF_SC1 + t] = rs1;
        wsf[OFF_SH1 + t] = fmaf(eb1[t] - em1[t], rs1, ebe1[t]);
        float rs2 = rsqrtf(ev2[t] + EPS) * eg2[t];
        wsf[OFF_SC2 + t] = rs2;
        wsf[OFF_SH2 + t] = fmaf(eb2[t] - em2[t], rs2, ebe2[t]);
    } else if (gid < 65536 + 4096 + 1024 + 64) {
        int t = gid - (65536 + 4096 + 1024);
        float rs = rsqrtf(pv[t] + EPS) * pg[t];
        wsf[OFF_SCP + t] = rs;
        wsf[OFF_SHP + t] = fmaf(pb1[t] - pm[t], rs, pbe[t]);
    } else if (gid < 65536 + 4096 + 1024 + 64 + 16) {
        gcnt[gid - (65536 + 4096 + 1024 + 64)] = 0;
    }
}

// ---------------- gate: MLP + softmax + top2 + list build ----------------
__global__ __launch_bounds__(256, 2) void k_gate(
    const int* __restrict__ sql, const float* __restrict__ sql_table,
    const float* __restrict__ gw1, const float* __restrict__ gb1,
    const float* __restrict__ gw2, const float* __restrict__ gb2,
    int* __restrict__ lidx, float* __restrict__ lw,
    int* __restrict__ gcnt, float* __restrict__ imp_part)
{
    __shared__ float sW1[GATE_IN * HID];   // 51200 B
    __shared__ float sW2[HID * KEXP];      // 4096 B
    __shared__ float sB1[HID];
    __shared__ float sB2[KEXP];
    __shared__ float s_imp[KEXP];
    __shared__ int s_cnt[KEXP];
    __shared__ int s_base[KEXP];
    int tid = threadIdx.x;
    for (int t = tid; t < GATE_IN * HID / 4; t += 256)
        ((float4*)sW1)[t] = ((const float4*)gw1)[t];
    for (int t = tid; t < HID * KEXP / 4; t += 256)
        ((float4*)sW2)[t] = ((const float4*)gw2)[t];
    if (tid < HID) sB1[tid] = gb1[tid];
    if (tid < KEXP) { sB2[tid] = gb2[tid]; s_imp[tid] = 0.f; s_cnt[tid] = 0; }
    __syncthreads();

    int b = blockIdx.x * 256 + tid;
    int si[NFIELD];
#pragma unroll
    for (int j = 0; j < NFIELD / 4; ++j) {
        int4 t = *(const int4*)(sql + (size_t)b * NFIELD + 4 * j);
        si[4 * j] = t.x; si[4 * j + 1] = t.y; si[4 * j + 2] = t.z; si[4 * j + 3] = t.w;
    }
    float xv[SQL_NEMB], xn[SQL_NEMB];
#pragma unroll
    for (int j = 0; j < SQL_NEMB / 2; ++j) {
        float2 t = *(const float2*)(sql_table + (size_t)si[0] * SQL_NEMB + 2 * j);
        xv[2 * j] = t.x; xv[2 * j + 1] = t.y;
    }
    float acc[HID];
#pragma unroll
    for (int h = 0; h < HID; ++h) acc[h] = 0.f;
    for (int f = 0; f < NFIELD; f += 2) {
        // prefetch field f+1
#pragma unroll
        for (int j = 0; j < SQL_NEMB / 2; ++j) {
            float2 t = *(const float2*)(sql_table + (size_t)si[f + 1] * SQL_NEMB + 2 * j);
            xn[2 * j] = t.x; xn[2 * j + 1] = t.y;
        }
#pragma unroll
        for (int i = 0; i < SQL_NEMB; ++i) {
            const float* wr = &sW1[(f * SQL_NEMB + i) * HID];
#pragma unroll
            for (int h = 0; h < HID; ++h) acc[h] = fmaf(xv[i], wr[h], acc[h]);
        }
        // prefetch field f+2
        if (f + 2 < NFIELD) {
#pragma unroll
            for (int j = 0; j < SQL_NEMB / 2; ++j) {
                float2 t = *(const float2*)(sql_table + (size_t)si[f + 2] * SQL_NEMB + 2 * j);
                xv[2 * j] = t.x; xv[2 * j + 1] = t.y;
            }
        }
#pragma unroll
        for (int i = 0; i < SQL_NEMB; ++i) {
            const float* wr = &sW1[((f + 1) * SQL_NEMB + i) * HID];
#pragma unroll
            for (int h = 0; h < HID; ++h) acc[h] = fmaf(xn[i], wr[h], acc[h]);
        }
    }
    float z[KEXP];
#pragma unroll
    for (int j = 0; j < KEXP; ++j) z[j] = sB2[j];
#pragma unroll
    for (int h = 0; h < HID; ++h) {
        float g = fmaxf(acc[h] + sB1[h], 0.f);
#pragma unroll
        for (int j = 0; j < KEXP; ++j) z[j] = fmaf(g, sW2[h * KEXP + j], z[j]);
    }
    // softmax denom
    float m = z[0];
#pragma unroll
    for (int j = 1; j < KEXP; ++j) m = fmaxf(m, z[j]);
    float s = 0.f;
#pragma unroll
    for (int j = 0; j < KEXP; ++j) s += expf(z[j] - m);
    // top-2 on logits (softmax is monotone)
    int i0 = 0; float m0 = z[0];
#pragma unroll
    for (int j = 1; j < KEXP; ++j) if (z[j] > m0) { m0 = z[j]; i0 = j; }
    int i1 = (i0 == 0) ? 1 : 0; float m1 = -3.4e38f;
#pragma unroll
    for (int j = 0; j < KEXP; ++j) if (j != i0 && z[j] > m1) { m1 = z[j]; i1 = j; }
    float v0 = expf(m0 - m) / s, v1 = expf(m1 - m) / s;
    float inv = 1.f / (v0 + v1 + 1e-9f);
    float w0 = v0 * inv, w1 = v1 * inv;

    atomicAdd(&s_imp[i0], w0);
    atomicAdd(&s_imp[i1], w1);
    int o0 = atomicAdd(&s_cnt[i0], 1);
    int o1 = atomicAdd(&s_cnt[i1], 1);
    __syncthreads();
    if (tid < KEXP) {
        imp_part[blockIdx.x * KEXP + tid] = s_imp[tid];
        s_base[tid] = atomicAdd(&gcnt[tid], s_cnt[tid]);
    }
    __syncthreads();
    int p0 = i0 * BB + s_base[i0] + o0;
    lidx[p0] = (b << 1);     lw[p0] = w0;
    int p1 = i1 * BB + s_base[i1] + o1;
    lidx[p1] = (b << 1) | 1; lw[p1] = w1;
}

// ---------------- loss from importance partials ----------------
__global__ void k_loss(const float* __restrict__ imp_part, float* __restrict__ out)
{
    __shared__ double simp[KEXP];
    int tid = threadIdx.x;
    if (tid < KEXP) {
        double s = 0.0;
        for (int blk = 0; blk < NBLK_GATE; ++blk) s += (double)imp_part[blk * KEXP + tid];
        simp[tid] = s;
    }
    __syncthreads();
    if (tid == 0) {
        double mean = 0.0;
        for (int j = 0; j < KEXP; ++j) mean += simp[j];
        mean /= KEXP;
        double var = 0.0;
        for (int j = 0; j < KEXP; ++j) { double d = simp[j] - mean; var += d * d; }
        var /= KEXP;
        out[BB] = (float)(var / (mean * mean + 1e-10));
    }
}

// ---------------- expert MLP over its sample list ----------------
__global__ __launch_bounds__(256, 2) void k_expert(
    const int* __restrict__ x, const float* __restrict__ itab,
    const float* __restrict__ ew1,
    const float* __restrict__ w2t,
    const float* __restrict__ sc1, const float* __restrict__ sh1,
    const float* __restrict__ sc2, const float* __restrict__ sh2,
    const int* __restrict__ lidx, const float* __restrict__ lw,
    const int* __restrict__ gcnt, float* __restrict__ hs)
{
    __shared__ float sW1[EXP_IN * HID];  // 51200 B
    __shared__ float sW2[HID * HID];     // 16384 B
    __shared__ float sS[4 * HID];        // sc1, sh1, sc2, sh2
    int k = blockIdx.y;
    int tid = threadIdx.x;
    {
        const float* W1 = ew1 + (size_t)k * (EXP_IN * HID);
        for (int t = tid; t < EXP_IN * HID / 4; t += 256)
            ((float4*)sW1)[t] = ((const float4*)W1)[t];
        const float* W2T = w2t + (size_t)k * (HID * HID);
        for (int t = tid; t < HID * HID / 4; t += 256)
            ((float4*)sW2)[t] = ((const float4*)W2T)[t];
        if (tid < HID) {
            sS[tid]           = sc1[k * HID + tid];
            sS[HID + tid]     = sh1[k * HID + tid];
            sS[2 * HID + tid] = sc2[k * HID + tid];
            sS[3 * HID + tid] = sh2[k * HID + tid];
        }
    }
    __syncthreads();
    int n = gcnt[k];
    for (int idx = blockIdx.x * blockDim.x + tid; idx < n;
         idx += gridDim.x * blockDim.x) {
        int e = lidx[k * BB + idx];
        float w = lw[k * BB + idx];
        int b = e >> 1, slot = e & 1;

        int xi[NFIELD];
#pragma unroll
        for (int j = 0; j < NFIELD / 4; ++j) {
            int4 t = *(const int4*)(x + (size_t)b * NFIELD + 4 * j);
            xi[4 * j] = t.x; xi[4 * j + 1] = t.y; xi[4 * j + 2] = t.z; xi[4 * j + 3] = t.w;
        }
        float xv[DATA_NEMB], xn[DATA_NEMB];
#pragma unroll
        for (int j = 0; j < DATA_NEMB / 2; ++j) {
            float2 t = *(const float2*)(itab + (size_t)xi[0] * DATA_NEMB + 2 * j);
            xv[2 * j] = t.x; xv[2 * j + 1] = t.y;
        }
        float acc[HID];
#pragma unroll
        for (int h = 0; h < HID; ++h) acc[h] = 0.f;
        for (int f = 0; f < NFIELD; f += 2) {
            // prefetch field f+1
#pragma unroll
            for (int j = 0; j < DATA_NEMB / 2; ++j) {
                float2 t = *(const float2*)(itab + (size_t)xi[f + 1] * DATA_NEMB + 2 * j);
                xn[2 * j] = t.x; xn[2 * j + 1] = t.y;
            }
#pragma unroll
            for (int i = 0; i < DATA_NEMB; ++i) {
                const float* wr = &sW1[(f * DATA_NEMB + i) * HID];
#pragma unroll
                for (int h = 0; h < HID; ++h) acc[h] = fmaf(xv[i], wr[h], acc[h]);
            }
            // prefetch field f+2
            if (f + 2 < NFIELD) {
#pragma unroll
                for (int j = 0; j < DATA_NEMB / 2; ++j) {
                    float2 t = *(const float2*)(itab + (size_t)xi[f + 2] * DATA_NEMB + 2 * j);
                    xv[2 * j] = t.x; xv[2 * j + 1] = t.y;
                }
            }
#pragma unroll
            for (int i = 0; i < DATA_NEMB; ++i) {
                const float* wr = &sW1[((f + 1) * DATA_NEMB + i) * HID];
#pragma unroll
                for (int h = 0; h < HID; ++h) acc[h] = fmaf(xn[i], wr[h], acc[h]);
            }
        }
        float h1[HID];
#pragma unroll
        for (int h = 0; h < HID; ++h)
            h1[h] = fmaxf(fmaf(acc[h], sS[h], sS[HID + h]), 0.f);

        float* outp = hs + ((size_t)b * 2 + slot) * HID;
        for (int g0 = 0; g0 < HID; g0 += 8) { // runtime loop, 8 outputs/iter
            float t8[8];
#pragma unroll
            for (int u = 0; u < 8; ++u) {
                float t = 0.f;
                const float* wr = &sW2[(g0 + u) * HID];
#pragma unroll
                for (int i = 0; i < HID; ++i) t = fmaf(h1[i], wr[i], t);
                int g = g0 + u;
                t8[u] = w * fmaxf(fmaf(t, sS[2 * HID + g], sS[3 * HID + g]), 0.f);
            }
            float4 v0; v0.x = t8[0]; v0.y = t8[1]; v0.z = t8[2]; v0.w = t8[3];
            float4 v1; v1.x = t8[4]; v1.y = t8[5]; v1.z = t8[6]; v1.w = t8[7];
            *(float4*)(outp + g0) = v0;
            *(float4*)(outp + g0 + 4) = v1;
        }
    }
}

// ---------------- predict head ----------------
__global__ __launch_bounds__(256, 2) void k_head(
    const float* __restrict__ hs, const float* __restrict__ pw1t,
    const float* __restrict__ scp, const float* __restrict__ shp,
    const float* __restrict__ pw2, const float* __restrict__ pb2,
    float* __restrict__ out)
{
    __shared__ float sPW[HID * HID]; // 16 KB
    __shared__ float sV[3 * HID];    // scp, shp, pw2
    int tid = threadIdx.x;
    for (int t = tid; t < HID * HID / 4; t += 256)
        ((float4*)sPW)[t] = ((const float4*)pw1t)[t];
    if (tid < HID) {
        sV[tid]           = scp[tid];
        sV[HID + tid]     = shp[tid];
        sV[2 * HID + tid] = pw2[tid];
    }
    __syncthreads();

    int b = blockIdx.x * 256 + tid;
    const float* hp = hs + (size_t)b * 128;
    float y[HID];
#pragma unroll
    for (int j = 0; j < HID / 4; ++j) {
        float4 a = *(const float4*)(hp + 4 * j);
        float4 c = *(const float4*)(hp + 64 + 4 * j);
        y[4 * j] = a.x + c.x; y[4 * j + 1] = a.y + c.y;
        y[4 * j + 2] = a.z + c.z; y[4 * j + 3] = a.w + c.w;
    }
    float o = pb2[0];
    for (int h0 = 0; h0 < HID; h0 += 8) { // runtime loop
#pragma unroll
        for (int u = 0; u < 8; ++u) {
            float t = 0.f;
            const float* wr = &sPW[(h0 + u) * HID];
#pragma unroll
            for (int i = 0; i < HID; ++i) t = fmaf(y[i], wr[i], t);
            float ph = fmaxf(fmaf(t, sV[h0 + u], sV[HID + h0 + u]), 0.f);
            o = fmaf(ph, sV[2 * HID + h0 + u], o);
        }
    }
    out[b] = o;
}

extern "C" void kernel_launch(void* const* d_in, const int* in_sizes, int n_in,
                              void* d_out, int out_size, void* d_ws, size_t ws_size,
                              hipStream_t stream) {
    const int*   x     = (const int*)d_in[0];
    const int*   sql   = (const int*)d_in[1];
    const float* itab  = (const float*)d_in[2];
    const float* stab  = (const float*)d_in[3];
    const float* gw1   = (const float*)d_in[4];
    const float* gb1   = (const float*)d_in[5];
    const float* gw2   = (const float*)d_in[6];
    const float* gb2   = (const float*)d_in[7];
    const float* ew1   = (const float*)d_in[8];
    const float* eb1   = (const float*)d_in[9];
    const float* eg1   = (const float*)d_in[10];
    const float* ebe1  = (const float*)d_in[11];
    const float* em1   = (const float*)d_in[12];
    const float* ev1   = (const float*)d_in[13];
    const float* ew2   = (const float*)d_in[14];
    const float* eb2   = (const float*)d_in[15];
    const float* eg2   = (const float*)d_in[16];
    const float* ebe2  = (const float*)d_in[17];
    const float* em2   = (const float*)d_in[18];
    const float* ev2   = (const float*)d_in[19];
    const float* pw1   = (const float*)d_in[20];
    const float* pb1   = (const float*)d_in[21];
    const float* pg    = (const float*)d_in[22];
    const float* pbe   = (const float*)d_in[23];
    const float* pm    = (const float*)d_in[24];
    const float* pv    = (const float*)d_in[25];
    const float* pw2   = (const float*)d_in[26];
    const float* pb2   = (const float*)d_in[27];

    float* wsf  = (float*)d_ws;
    int*   wsi  = (int*)d_ws;
    int*   gcnt = wsi + OFF_GCNT;
    float* sc1  = wsf + OFF_SC1;
    float* sh1  = wsf + OFF_SH1;
    float* sc2  = wsf + OFF_SC2;
    float* sh2  = wsf + OFF_SH2;
    float* scp  = wsf + OFF_SCP;
    float* shp  = wsf + OFF_SHP;
    float* w2t  = wsf + OFF_W2T;
    float* pw1t = wsf + OFF_PW1T;
    float* imp  = wsf + OFF_IMP;
    int*   lidx = wsi + OFF_LIDX;
    float* lw   = wsf + OFF_LW;
    float* hs   = wsf + OFF_HS;
    float* out  = (float*)d_out;

    k_prep<<<277, 256, 0, stream>>>(ew2, pw1, eb1, eg1, ebe1, em1, ev1,
                                    eb2, eg2, ebe2, em2, ev2,
                                    pb1, pg, pbe, pm, pv, wsf, gcnt);
    k_gate<<<NBLK_GATE, 256, 0, stream>>>(sql, stab, gw1, gb1, gw2, gb2,
                                          lidx, lw, gcnt, imp);
    k_loss<<<1, 64, 0, stream>>>(imp, out);
    dim3 g3(32, KEXP);
    k_expert<<<g3, 256, 0, stream>>>(x, itab, ew1, w2t, sc1, sh1, sc2, sh2,
                                     lidx, lw, gcnt, hs);
    k_head<<<NBLK_GATE, 256, 0, stream>>>(hs, pw1t, scp, shp, pw2, pb2, out);
}

// Round 3
// 248.619 us; speedup vs baseline: 12.4356x; 12.4356x over previous
//
#include <hip/hip_runtime.h>
#include <hip/hip_bf16.h>

#define BB 65536
#define NFIELD 20
#define DATA_NEMB 10
#define SQL_NEMB 10
#define HID 64
#define KEXP 16
#define EPS 1e-5f
#define NBLK_GATE 512
#define NCHUNK (BB / 64)
#define GATE_IN (NFIELD * SQL_NEMB)
#define EXP_IN (NFIELD * DATA_NEMB)

// ---- ws layout (element offsets, 4B elements) ----
#define OFF_GCNT 0                      // 16 int
#define OFF_SC1 64                      // 16*64 f32
#define OFF_SH1 (OFF_SC1 + 1024)
#define OFF_SC2 (OFF_SH1 + 1024)
#define OFF_SH2 (OFF_SC2 + 1024)
#define OFF_SCP (OFF_SH2 + 1024)        // 64
#define OFF_SHP (OFF_SCP + 64)          // 64
#define OFF_IMP (OFF_SHP + 64)          // 512*16 importance partials
#define OFF_LIDX (OFF_IMP + 8192)       // 16*B int
#define OFF_LW (OFF_LIDX + (16 * BB))   // 16*B f32
#define OFF_HS (OFF_LW + (16 * BB))     // 2B*64 f32 (weighted h2 per slot)
#define OFF_H1 (OFF_HS + (2 * BB * 64)) // 2B*64 f32 (h1 per slot)

// ---------------- prep: BN folds + counter zero ----------------
__global__ __launch_bounds__(256) void k_prep(
    const float* __restrict__ eb1, const float* __restrict__ eg1,
    const float* __restrict__ ebe1, const float* __restrict__ em1,
    const float* __restrict__ ev1,
    const float* __restrict__ eb2, const float* __restrict__ eg2,
    const float* __restrict__ ebe2, const float* __restrict__ em2,
    const float* __restrict__ ev2,
    const float* __restrict__ pb1, const float* __restrict__ pg,
    const float* __restrict__ pbe, const float* __restrict__ pm,
    const float* __restrict__ pv,
    float* __restrict__ wsf, int* __restrict__ gcnt)
{
    int gid = blockIdx.x * 256 + threadIdx.x;
    if (gid < 1024) {
        int t = gid; // k*64+h
        float rs1 = rsqrtf(ev1[t] + EPS) * eg1[t];
        wsf[OFF_SC1 + t] = rs1;
        wsf[OFF_SH1 + t] = fmaf(eb1[t] - em1[t], rs1, ebe1[t]);
        float rs2 = rsqrtf(ev2[t] + EPS) * eg2[t];
        wsf[OFF_SC2 + t] = rs2;
        wsf[OFF_SH2 + t] = fmaf(eb2[t] - em2[t], rs2, ebe2[t]);
    } else if (gid < 1024 + 64) {
        int t = gid - 1024;
        float rs = rsqrtf(pv[t] + EPS) * pg[t];
        wsf[OFF_SCP + t] = rs;
        wsf[OFF_SHP + t] = fmaf(pb1[t] - pm[t], rs, pbe[t]);
    } else if (gid < 1024 + 64 + 16) {
        gcnt[gid - (1024 + 64)] = 0;
    }
}

// ---------------- gate: sliced MLP + softmax + top2 + list build ----------------
__global__ __launch_bounds__(256, 2) void k_gate(
    const int* __restrict__ sql, const float* __restrict__ sql_table,
    const float* __restrict__ gw1, const float* __restrict__ gb1,
    const float* __restrict__ gw2, const float* __restrict__ gb2,
    int* __restrict__ lidx, float* __restrict__ lw,
    int* __restrict__ gcnt, float* __restrict__ imp_part)
{
    __shared__ float sW1[GATE_IN * HID];    // 51200 B
    __shared__ float sW2[HID * KEXP];       // 4096 B
    __shared__ float sB1[HID];
    __shared__ float sB2[KEXP];
    __shared__ float exch[4 * KEXP * 65];   // 16640 B, [wave][j][65]
    __shared__ float s_imp[KEXP];
    __shared__ int s_cnt[KEXP];
    __shared__ int s_base[KEXP];
    int tid = threadIdx.x;
    int wid = tid >> 6, lane = tid & 63;
    int hbase = wid * 16;
    for (int t = tid; t < GATE_IN * HID / 4; t += 256)
        ((float4*)sW1)[t] = ((const float4*)gw1)[t];
    for (int t = tid; t < HID * KEXP / 4; t += 256)
        ((float4*)sW2)[t] = ((const float4*)gw2)[t];
    if (tid < HID) sB1[tid] = gb1[tid];
    if (tid < KEXP) { sB2[tid] = gb2[tid]; s_imp[tid] = 0.f; }
    __syncthreads();

    for (int c = blockIdx.x; c < NCHUNK; c += gridDim.x) {
        int b = c * 64 + lane;
        int si[NFIELD];
#pragma unroll
        for (int j = 0; j < NFIELD / 4; ++j) {
            int4 t = *(const int4*)(sql + (size_t)b * NFIELD + 4 * j);
            si[4 * j] = t.x; si[4 * j + 1] = t.y; si[4 * j + 2] = t.z; si[4 * j + 3] = t.w;
        }
        float xv[SQL_NEMB], xn[SQL_NEMB];
#pragma unroll
        for (int j = 0; j < SQL_NEMB / 2; ++j) {
            float2 t = *(const float2*)(sql_table + (size_t)si[0] * SQL_NEMB + 2 * j);
            xv[2 * j] = t.x; xv[2 * j + 1] = t.y;
        }
        float acc[16];
#pragma unroll
        for (int h = 0; h < 16; ++h) acc[h] = 0.f;
        for (int f = 0; f < NFIELD; f += 2) {
#pragma unroll
            for (int j = 0; j < SQL_NEMB / 2; ++j) {
                float2 t = *(const float2*)(sql_table + (size_t)si[f + 1] * SQL_NEMB + 2 * j);
                xn[2 * j] = t.x; xn[2 * j + 1] = t.y;
            }
#pragma unroll
            for (int i = 0; i < SQL_NEMB; ++i) {
                const float* wr = &sW1[(f * SQL_NEMB + i) * HID + hbase];
#pragma unroll
                for (int h = 0; h < 16; ++h) acc[h] = fmaf(xv[i], wr[h], acc[h]);
            }
            if (f + 2 < NFIELD) {
#pragma unroll
                for (int j = 0; j < SQL_NEMB / 2; ++j) {
                    float2 t = *(const float2*)(sql_table + (size_t)si[f + 2] * SQL_NEMB + 2 * j);
                    xv[2 * j] = t.x; xv[2 * j + 1] = t.y;
                }
            }
#pragma unroll
            for (int i = 0; i < SQL_NEMB; ++i) {
                const float* wr = &sW1[((f + 1) * SQL_NEMB + i) * HID + hbase];
#pragma unroll
                for (int h = 0; h < 16; ++h) acc[h] = fmaf(xn[i], wr[h], acc[h]);
            }
        }
        // partial logits over this wave's 16 hidden units
        float pz[KEXP];
#pragma unroll
        for (int j = 0; j < KEXP; ++j) pz[j] = 0.f;
#pragma unroll
        for (int hh = 0; hh < 16; ++hh) {
            float g = fmaxf(acc[hh] + sB1[hbase + hh], 0.f);
            const float* wr = &sW2[(hbase + hh) * KEXP];
#pragma unroll
            for (int j = 0; j < KEXP; ++j) pz[j] = fmaf(g, wr[j], pz[j]);
        }
#pragma unroll
        for (int j = 0; j < KEXP; ++j)
            exch[(wid * KEXP + j) * 65 + lane] = pz[j];
        __syncthreads();

        if (wid == 0) {
            float z[KEXP];
#pragma unroll
            for (int j = 0; j < KEXP; ++j)
                z[j] = sB2[j] + exch[j * 65 + lane]
                     + exch[(KEXP + j) * 65 + lane]
                     + exch[(2 * KEXP + j) * 65 + lane]
                     + exch[(3 * KEXP + j) * 65 + lane];
            float m = z[0];
#pragma unroll
            for (int j = 1; j < KEXP; ++j) m = fmaxf(m, z[j]);
            float s = 0.f;
#pragma unroll
            for (int j = 0; j < KEXP; ++j) s += expf(z[j] - m);
            int i0 = 0; float m0 = z[0];
#pragma unroll
            for (int j = 1; j < KEXP; ++j) if (z[j] > m0) { m0 = z[j]; i0 = j; }
            int i1 = (i0 == 0) ? 1 : 0; float m1 = -3.4e38f;
#pragma unroll
            for (int j = 0; j < KEXP; ++j) if (j != i0 && z[j] > m1) { m1 = z[j]; i1 = j; }
            float v0 = expf(m0 - m) / s, v1 = expf(m1 - m) / s;
            float inv = 1.f / (v0 + v1 + 1e-9f);
            float w0 = v0 * inv, w1 = v1 * inv;

            if (lane < KEXP) s_cnt[lane] = 0;
            atomicAdd(&s_imp[i0], w0);
            atomicAdd(&s_imp[i1], w1);
            int o0 = atomicAdd(&s_cnt[i0], 1);
            int o1 = atomicAdd(&s_cnt[i1], 1);
            if (lane < KEXP) s_base[lane] = atomicAdd(&gcnt[lane], s_cnt[lane]);
            int p0 = i0 * BB + s_base[i0] + o0;
            lidx[p0] = (b << 1);     lw[p0] = w0;
            int p1 = i1 * BB + s_base[i1] + o1;
            lidx[p1] = (b << 1) | 1; lw[p1] = w1;
        }
        __syncthreads();
    }
    if (tid < KEXP) imp_part[blockIdx.x * KEXP + tid] = s_imp[tid];
}

// ---------------- loss from importance partials ----------------
__global__ __launch_bounds__(256) void k_loss(const float* __restrict__ imp_part,
                                              float* __restrict__ out)
{
    __shared__ double sred[16][17];
    __shared__ double simp[KEXP];
    int tid = threadIdx.x;
    int j = tid & 15, g = tid >> 4;
    double s = 0.0;
    for (int blk = g; blk < NBLK_GATE; blk += 16) s += (double)imp_part[blk * KEXP + j];
    sred[g][j] = s;
    __syncthreads();
    if (tid < KEXP) {
        double t = 0.0;
#pragma unroll
        for (int gg = 0; gg < 16; ++gg) t += sred[gg][tid];
        simp[tid] = t;
    }
    __syncthreads();
    if (tid == 0) {
        double mean = 0.0;
        for (int jj = 0; jj < KEXP; ++jj) mean += simp[jj];
        mean /= KEXP;
        double var = 0.0;
        for (int jj = 0; jj < KEXP; ++jj) { double d = simp[jj] - mean; var += d * d; }
        var /= KEXP;
        out[BB] = (float)(var / (mean * mean + 1e-10));
    }
}

// ---------------- expert layer 1 (sliced): emb gather + W1 + BN/ReLU -> h1 ----------------
__global__ __launch_bounds__(256, 2) void k_exp1(
    const int* __restrict__ x, const float* __restrict__ itab,
    const float* __restrict__ ew1,
    const float* __restrict__ sc1, const float* __restrict__ sh1,
    const int* __restrict__ lidx, const int* __restrict__ gcnt,
    float* __restrict__ h1buf)
{
    __shared__ float sW1[EXP_IN * HID]; // 51200 B
    __shared__ float sSc[HID], sSh[HID];
    int k = blockIdx.y;
    int tid = threadIdx.x;
    int wid = tid >> 6, lane = tid & 63;
    int hbase = wid * 16;
    {
        const float* W1 = ew1 + (size_t)k * (EXP_IN * HID);
        for (int t = tid; t < EXP_IN * HID / 4; t += 256)
            ((float4*)sW1)[t] = ((const float4*)W1)[t];
        if (tid < HID) { sSc[tid] = sc1[k * HID + tid]; sSh[tid] = sh1[k * HID + tid]; }
    }
    __syncthreads();
    int n = gcnt[k];
    for (int base = blockIdx.x * 64; base < n; base += gridDim.x * 64) {
        int it = base + lane;
        if (it >= n) continue;
        int e = lidx[k * BB + it];
        int b = e >> 1;

        int xi[NFIELD];
#pragma unroll
        for (int j = 0; j < NFIELD / 4; ++j) {
            int4 t = *(const int4*)(x + (size_t)b * NFIELD + 4 * j);
            xi[4 * j] = t.x; xi[4 * j + 1] = t.y; xi[4 * j + 2] = t.z; xi[4 * j + 3] = t.w;
        }
        float xv[DATA_NEMB], xn[DATA_NEMB];
#pragma unroll
        for (int j = 0; j < DATA_NEMB / 2; ++j) {
            float2 t = *(const float2*)(itab + (size_t)xi[0] * DATA_NEMB + 2 * j);
            xv[2 * j] = t.x; xv[2 * j + 1] = t.y;
        }
        float acc[16];
#pragma unroll
        for (int h = 0; h < 16; ++h) acc[h] = 0.f;
        for (int f = 0; f < NFIELD; f += 2) {
#pragma unroll
            for (int j = 0; j < DATA_NEMB / 2; ++j) {
                float2 t = *(const float2*)(itab + (size_t)xi[f + 1] * DATA_NEMB + 2 * j);
                xn[2 * j] = t.x; xn[2 * j + 1] = t.y;
            }
#pragma unroll
            for (int i = 0; i < DATA_NEMB; ++i) {
                const float* wr = &sW1[(f * DATA_NEMB + i) * HID + hbase];
#pragma unroll
                for (int h = 0; h < 16; ++h) acc[h] = fmaf(xv[i], wr[h], acc[h]);
            }
            if (f + 2 < NFIELD) {
#pragma unroll
                for (int j = 0; j < DATA_NEMB / 2; ++j) {
                    float2 t = *(const float2*)(itab + (size_t)xi[f + 2] * DATA_NEMB + 2 * j);
                    xv[2 * j] = t.x; xv[2 * j + 1] = t.y;
                }
            }
#pragma unroll
            for (int i = 0; i < DATA_NEMB; ++i) {
                const float* wr = &sW1[((f + 1) * DATA_NEMB + i) * HID + hbase];
#pragma unroll
                for (int h = 0; h < 16; ++h) acc[h] = fmaf(xn[i], wr[h], acc[h]);
            }
        }
        float* outp = h1buf + (size_t)e * HID + hbase;
#pragma unroll
        for (int q = 0; q < 4; ++q) {
            float4 v;
            v.x = fmaxf(fmaf(acc[4 * q + 0], sSc[hbase + 4 * q + 0], sSh[hbase + 4 * q + 0]), 0.f);
            v.y = fmaxf(fmaf(acc[4 * q + 1], sSc[hbase + 4 * q + 1], sSh[hbase + 4 * q + 1]), 0.f);
            v.z = fmaxf(fmaf(acc[4 * q + 2], sSc[hbase + 4 * q + 2], sSh[hbase + 4 * q + 2]), 0.f);
            v.w = fmaxf(fmaf(acc[4 * q + 3], sSc[hbase + 4 * q + 3], sSh[hbase + 4 * q + 3]), 0.f);
            *(float4*)(outp + 4 * q) = v;
        }
    }
}

// ---------------- expert layer 2 (sliced): h1 @ W2 + BN/ReLU, * gate -> hs ----------------
__global__ __launch_bounds__(256, 2) void k_exp2(
    const float* __restrict__ ew2,
    const float* __restrict__ sc2, const float* __restrict__ sh2,
    const int* __restrict__ lidx, const float* __restrict__ lw,
    const int* __restrict__ gcnt,
    const float* __restrict__ h1buf, float* __restrict__ hs)
{
    __shared__ float sW2[HID * HID]; // ew2[k] in [i][g] layout, 16384 B
    __shared__ float sSc[HID], sSh[HID];
    int k = blockIdx.y;
    int tid = threadIdx.x;
    int wid = tid >> 6, lane = tid & 63;
    int gbase = wid * 16;
    {
        const float* W2 = ew2 + (size_t)k * (HID * HID);
        for (int t = tid; t < HID * HID / 4; t += 256)
            ((float4*)sW2)[t] = ((const float4*)W2)[t];
        if (tid < HID) { sSc[tid] = sc2[k * HID + tid]; sSh[tid] = sh2[k * HID + tid]; }
    }
    __syncthreads();
    int n = gcnt[k];
    for (int base = blockIdx.x * 64; base < n; base += gridDim.x * 64) {
        int it = base + lane;
        if (it >= n) continue;
        int e = lidx[k * BB + it];
        float w = lw[k * BB + it];
        const float* hp = h1buf + (size_t)e * HID;
        float4 hv = *(const float4*)(hp);
        float acc[16];
#pragma unroll
        for (int g = 0; g < 16; ++g) acc[g] = 0.f;
#pragma unroll
        for (int i0 = 0; i0 < 16; ++i0) {
            float4 cur = hv;
            if (i0 < 15) hv = *(const float4*)(hp + 4 * (i0 + 1));
            float hvv[4] = {cur.x, cur.y, cur.z, cur.w};
#pragma unroll
            for (int u = 0; u < 4; ++u) {
                const float* wr = &sW2[(4 * i0 + u) * HID + gbase];
#pragma unroll
                for (int g = 0; g < 16; ++g) acc[g] = fmaf(hvv[u], wr[g], acc[g]);
            }
        }
        float* outp = hs + (size_t)e * HID + gbase;
#pragma unroll
        for (int q = 0; q < 4; ++q) {
            float4 v;
            v.x = w * fmaxf(fmaf(acc[4 * q + 0], sSc[gbase + 4 * q + 0], sSh[gbase + 4 * q + 0]), 0.f);
            v.y = w * fmaxf(fmaf(acc[4 * q + 1], sSc[gbase + 4 * q + 1], sSh[gbase + 4 * q + 1]), 0.f);
            v.z = w * fmaxf(fmaf(acc[4 * q + 2], sSc[gbase + 4 * q + 2], sSh[gbase + 4 * q + 2]), 0.f);
            v.w = w * fmaxf(fmaf(acc[4 * q + 3], sSc[gbase + 4 * q + 3], sSh[gbase + 4 * q + 3]), 0.f);
            *(float4*)(outp + 4 * q) = v;
        }
    }
}

// ---------------- predict head (sliced) ----------------
__global__ __launch_bounds__(256, 2) void k_head(
    const float* __restrict__ hs, const float* __restrict__ pw1,
    const float* __restrict__ scp, const float* __restrict__ shp,
    const float* __restrict__ pw2, const float* __restrict__ pb2,
    float* __restrict__ out)
{
    __shared__ float sPW[HID * HID]; // pw1 in [i][g] layout, 16 KB
    __shared__ float sc[HID], sh[HID], sw2[HID];
    __shared__ float pex[4][64];
    int tid = threadIdx.x;
    int wid = tid >> 6, lane = tid & 63;
    int gbase = wid * 16;
    for (int t = tid; t < HID * HID / 4; t += 256)
        ((float4*)sPW)[t] = ((const float4*)pw1)[t];
    if (tid < HID) { sc[tid] = scp[tid]; sh[tid] = shp[tid]; sw2[tid] = pw2[tid]; }
    __syncthreads();

    for (int c = blockIdx.x; c < NCHUNK; c += gridDim.x) {
        int b = c * 64 + lane;
        const float* hp = hs + (size_t)b * 128;
        float acc[16];
#pragma unroll
        for (int g = 0; g < 16; ++g) acc[g] = 0.f;
#pragma unroll
        for (int i0 = 0; i0 < 16; ++i0) {
            float4 a = *(const float4*)(hp + 4 * i0);
            float4 d = *(const float4*)(hp + 64 + 4 * i0);
            float y4[4] = {a.x + d.x, a.y + d.y, a.z + d.z, a.w + d.w};
#pragma unroll
            for (int u = 0; u < 4; ++u) {
                const float* wr = &sPW[(4 * i0 + u) * HID + gbase];
#pragma unroll
                for (int g = 0; g < 16; ++g) acc[g] = fmaf(y4[u], wr[g], acc[g]);
            }
        }
        float po = 0.f;
#pragma unroll
        for (int g = 0; g < 16; ++g) {
            float ph = fmaxf(fmaf(acc[g], sc[gbase + g], sh[gbase + g]), 0.f);
            po = fmaf(ph, sw2[gbase + g], po);
        }
        pex[wid][lane] = po;
        __syncthreads();
        if (wid == 0)
            out[b] = pb2[0] + pex[0][lane] + pex[1][lane] + pex[2][lane] + pex[3][lane];
        __syncthreads();
    }
}

extern "C" void kernel_launch(void* const* d_in, const int* in_sizes, int n_in,
                              void* d_out, int out_size, void* d_ws, size_t ws_size,
                              hipStream_t stream) {
    const int*   x     = (const int*)d_in[0];
    const int*   sql   = (const int*)d_in[1];
    const float* itab  = (const float*)d_in[2];
    const float* stab  = (const float*)d_in[3];
    const float* gw1   = (const float*)d_in[4];
    const float* gb1   = (const float*)d_in[5];
    const float* gw2   = (const float*)d_in[6];
    const float* gb2   = (const float*)d_in[7];
    const float* ew1   = (const float*)d_in[8];
    const float* eb1   = (const float*)d_in[9];
    const float* eg1   = (const float*)d_in[10];
    const float* ebe1  = (const float*)d_in[11];
    const float* em1   = (const float*)d_in[12];
    const float* ev1   = (const float*)d_in[13];
    const float* ew2   = (const float*)d_in[14];
    const float* eb2   = (const float*)d_in[15];
    const float* eg2   = (const float*)d_in[16];
    const float* ebe2  = (const float*)d_in[17];
    const float* em2   = (const float*)d_in[18];
    const float* ev2   = (const float*)d_in[19];
    const float* pw1   = (const float*)d_in[20];
    const float* pb1   = (const float*)d_in[21];
    const float* pg    = (const float*)d_in[22];
    const float* pbe   = (const float*)d_in[23];
    const float* pm    = (const float*)d_in[24];
    const float* pv    = (const float*)d_in[25];
    const float* pw2   = (const float*)d_in[26];
    const float* pb2   = (const float*)d_in[27];

    float* wsf  = (float*)d_ws;
    int*   wsi  = (int*)d_ws;
    int*   gcnt = wsi + OFF_GCNT;
    float* sc1  = wsf + OFF_SC1;
    float* sh1  = wsf + OFF_SH1;
    float* sc2  = wsf + OFF_SC2;
    float* sh2  = wsf + OFF_SH2;
    float* scp  = wsf + OFF_SCP;
    float* shp  = wsf + OFF_SHP;
    float* imp  = wsf + OFF_IMP;
    int*   lidx = wsi + OFF_LIDX;
    float* lw   = wsf + OFF_LW;
    float* hs   = wsf + OFF_HS;
    float* h1b  = wsf + OFF_H1;
    float* out  = (float*)d_out;

    k_prep<<<5, 256, 0, stream>>>(eb1, eg1, ebe1, em1, ev1,
                                  eb2, eg2, ebe2, em2, ev2,
                                  pb1, pg, pbe, pm, pv, wsf, gcnt);
    k_gate<<<NBLK_GATE, 256, 0, stream>>>(sql, stab, gw1, gb1, gw2, gb2,
                                          lidx, lw, gcnt, imp);
    k_loss<<<1, 256, 0, stream>>>(imp, out);
    dim3 g1(64, KEXP);
    k_exp1<<<g1, 256, 0, stream>>>(x, itab, ew1, sc1, sh1, lidx, gcnt, h1b);
    dim3 g2(64, KEXP);
    k_exp2<<<g2, 256, 0, stream>>>(ew2, sc2, sh2, lidx, lw, gcnt, h1b, hs);
    k_head<<<1024, 256, 0, stream>>>(hs, pw1, scp, shp, pw2, pb2, out);
}